// Round 14
// baseline (31.625 us; speedup 1.0000x reference)
//
#include <hip/hip_runtime.h>
#include <hip/hip_bf16.h>
#include <math.h>

#define TAGS   20
#define TSTART (TAGS - 2)
#define TSTOP  (TAGS - 1)

constexpr float  LOG2E = 1.4426950408889634f;
constexpr float  LN2f  = 0.6931471805599453f;
constexpr double LN2d  = 0.69314718055994530942;

typedef __attribute__((ext_vector_type(8)))  short short8;
typedef __attribute__((ext_vector_type(16))) float f32x16;
union U4 { unsigned int u[4]; short8 v; };

// f32x2 -> packed bf16x2, round-half-up (+0x8000 then high halves via one
// v_perm_b32) — validated rounds 7/8/10/11/13, absmax 0.0. 3 VALU ops.
__device__ __forceinline__ unsigned int pk2(float lo, float hi) {
    unsigned int a = __float_as_uint(hi) + 0x8000u;
    unsigned int b = __float_as_uint(lo) + 0x8000u;
#if __has_builtin(__builtin_amdgcn_perm)
    return __builtin_amdgcn_perm(a, b, 0x07060302u);   // {a[31:16], b[31:16]}
#else
    return (a & 0xFFFF0000u) | (b >> 16);
#endif
}
#if __has_builtin(__builtin_amdgcn_exp2f)
__device__ __forceinline__ float fexp2(float x) { return __builtin_amdgcn_exp2f(x); }
#else
__device__ __forceinline__ float fexp2(float x) { return exp2f(x); }
#endif
#if __has_builtin(__builtin_amdgcn_logf)
__device__ __forceinline__ float flog2(float x) { return __builtin_amdgcn_logf(x); }
#else
__device__ __forceinline__ float flog2(float x) { return log2f(x); }
#endif
__device__ __forceinline__ float frcp(float x) { return __builtin_amdgcn_rcpf(x); }
__device__ __forceinline__ float bcast(float v, int srclane) {
    return __int_as_float(__builtin_amdgcn_readlane(__float_as_int(v), srclane));
}

// 32x32x16 split-half A/B k-slot base (validated rounds 11/13, absmax 0.0).
__device__ __forceinline__ int kbase(int p, int h) {
    return (p < 2) ? (4 * h + 2 * p) : (8 + 4 * h + 2 * (p - 2));
}
// 32x32 C/D row for reg j, lane-half h (guide-verified m74/m101)
__device__ __forceinline__ int crow(int j, int h) {
    return (j & 3) + 8 * (j >> 2) + 4 * h;
}

#define EFSTRIDE 36   // ef row stride (floats): 16B-aligned, bank-spread stores

// ========================== FUSED KERNEL ==================================
// Round-13 body (best measured: 27.9us, absmax 0.0), single-dispatch tail:
// deterministic fixed-point atomic accumulation (r8-validated) replaces the
// partial[] + reduce-kernel finish. Last-arriving block writes d_out.
__global__ __launch_bounds__(512)
void crf_fused_kernel(const float* __restrict__ feats,
                      const float* __restrict__ Tm,
                      const int*   __restrict__ tags,
                      const int*   __restrict__ lengths,
                      unsigned long long* __restrict__ acc,
                      unsigned int*       __restrict__ cnt,
                      float*              __restrict__ out,
                      int L)
{
    __shared__ float  smem[16 * 1152];   // 72 KB: ef staging; later tree slots (stride 1088)
    __shared__ float  sv[32];
    __shared__ int    EsX[8];
    __shared__ float  gred[8];
    __shared__ double fwd_sh;

    const int b    = blockIdx.x;
    const int tid  = threadIdx.x;
    const int w    = tid >> 6;
    const int lane = tid & 63;
    const int m    = lane & 31;          // output row (A) / column (C,B)
    const int h    = lane >> 5;          // lane half
    const int len  = lengths[b];

    // ---- stage ef = 2^(feat*log2e): lane (h,r) owns chunk w+8h, row r ----
    // 5 aligned float4 loads, 20 exp2, 8 float4 LDS stores. No divisions.
    // Wave w reads only its own staged chunks -> same-wave DS ordering,
    // no barrier needed (r8/r10/r13-validated).
    {
        const int r = lane & 31;
        const int c = w + 8 * (lane >> 5);
        float* efc = smem + c * 1152;
        const float4* p = reinterpret_cast<const float4*>(
            feats + ((size_t)b * L + (size_t)c * 32 + r) * TAGS);
        float4 o[5];
        #pragma unroll
        for (int j = 0; j < 5; ++j) {
            float4 v = p[j];
            o[j].x = fexp2(v.x * LOG2E); o[j].y = fexp2(v.y * LOG2E);
            o[j].z = fexp2(v.z * LOG2E); o[j].w = fexp2(v.w * LOG2E);
        }
        float4* q = reinterpret_cast<float4*>(efc + r * EFSTRIDE);
        #pragma unroll
        for (int j = 0; j < 5; ++j) q[j] = o[j];
        float4 z4 = make_float4(0.f, 0.f, 0.f, 0.f);
        q[5] = z4; q[6] = z4; q[7] = z4; q[8] = z4;
    }

    // ---- constant A fragments: A1 = 2^T[:,k<16], A2 = 2^T[:,k>=16] ----
    U4 A1g, A2g;
    #pragma unroll
    for (int p = 0; p < 4; ++p) {
        int r = kbase(p, h);
        float a0 = (m < TAGS && r     < TAGS) ? fexp2(Tm[m * TAGS + r]      * LOG2E) : 0.f;
        float a1 = (m < TAGS && r + 1 < TAGS) ? fexp2(Tm[m * TAGS + r + 1]  * LOG2E) : 0.f;
        float b0 = (m < TAGS && r + 16 < TAGS) ? fexp2(Tm[m * TAGS + r + 16] * LOG2E) : 0.f;
        float b1 = (m < TAGS && r + 17 < TAGS) ? fexp2(Tm[m * TAGS + r + 17] * LOG2E) : 0.f;
        A1g.u[p] = pk2(a0, a1);
        A2g.u[p] = pk2(b0, b1);
    }

    // step: C <- ET * (D_l * C) via 2 MFMAs (C-in chained)
    auto step = [&](f32x16& C, const float* efc, int t) {
        const float* row = efc + t * EFSTRIDE;
        float4 ea = *reinterpret_cast<const float4*>(row + 4 * h);
        float4 eb = *reinterpret_cast<const float4*>(row + 8 + 4 * h);
        float4 ec = *reinterpret_cast<const float4*>(row + 16 + 4 * h);
        float4 ed = *reinterpret_cast<const float4*>(row + 24 + 4 * h);
        U4 B1, B2;
        B1.u[0] = pk2(C[0]  * ea.x, C[1]  * ea.y);
        B1.u[1] = pk2(C[2]  * ea.z, C[3]  * ea.w);
        B1.u[2] = pk2(C[4]  * eb.x, C[5]  * eb.y);
        B1.u[3] = pk2(C[6]  * eb.z, C[7]  * eb.w);
        B2.u[0] = pk2(C[8]  * ec.x, C[9]  * ec.y);
        B2.u[1] = pk2(C[10] * ec.z, C[11] * ec.w);
        B2.u[2] = pk2(C[12] * ed.x, C[13] * ed.y);
        B2.u[3] = pk2(C[14] * ed.z, C[15] * ed.w);
        f32x16 z = {0.f,0.f,0.f,0.f,0.f,0.f,0.f,0.f,0.f,0.f,0.f,0.f,0.f,0.f,0.f,0.f};
        f32x16 t1 = __builtin_amdgcn_mfma_f32_32x32x16_bf16(A1g.v, B1.v, z,  0, 0, 0);
        C         = __builtin_amdgcn_mfma_f32_32x32x16_bf16(A2g.v, B2.v, t1, 0, 0, 0);
    };
    auto strip = [&](f32x16& C) -> int {
        float pr = ((C[0]+C[1])+(C[2]+C[3])) + ((C[4]+C[5])+(C[6]+C[7]))
                 + ((C[8]+C[9])+(C[10]+C[11])) + ((C[12]+C[13])+(C[14]+C[15]));
        int pb = __builtin_amdgcn_readfirstlane(__float_as_int(pr)); // col0 half-sum, >0
        int ex = ((pb >> 23) & 0xFF) - 127;
        float s = __uint_as_float((unsigned)(127 - ex) << 23);       // 2^-ex
        #pragma unroll
        for (int j = 0; j < 16; ++j) C[j] *= s;
        return ex;
    };
    auto xwrP = [&](float* Xs, const f32x16& C) {       // row-major, stride 34
        #pragma unroll
        for (int j = 0; j < 16; ++j) Xs[crow(j, h) * 34 + m] = C[j];
    };
    auto prodP = [&](const float* Xs, f32x16& C) -> int {  // C <- X * C
        U4 Ax1, Ax2;
        #pragma unroll
        for (int p = 0; p < 4; ++p) {
            int r = kbase(p, h);
            float2 x1 = *reinterpret_cast<const float2*>(&Xs[m * 34 + r]);
            float2 x2 = *reinterpret_cast<const float2*>(&Xs[m * 34 + r + 16]);
            Ax1.u[p] = pk2(x1.x, x1.y);
            Ax2.u[p] = pk2(x2.x, x2.y);
        }
        U4 B1, B2;
        B1.u[0] = pk2(C[0],  C[1]);
        B1.u[1] = pk2(C[2],  C[3]);
        B1.u[2] = pk2(C[4],  C[5]);
        B1.u[3] = pk2(C[6],  C[7]);
        B2.u[0] = pk2(C[8],  C[9]);
        B2.u[1] = pk2(C[10], C[11]);
        B2.u[2] = pk2(C[12], C[13]);
        B2.u[3] = pk2(C[14], C[15]);
        f32x16 z = {0.f,0.f,0.f,0.f,0.f,0.f,0.f,0.f,0.f,0.f,0.f,0.f,0.f,0.f,0.f,0.f};
        f32x16 t1 = __builtin_amdgcn_mfma_f32_32x32x16_bf16(Ax1.v, B1.v, z,  0, 0, 0);
        C         = __builtin_amdgcn_mfma_f32_32x32x16_bf16(Ax2.v, B2.v, t1, 0, 0, 0);
        return strip(C);
    };
    auto xwr = [&](int slot, const f32x16& C, int E) {
        xwrP(smem + slot * 1088, C);
        if (lane == 0) EsX[slot] = E;
    };
    auto prod = [&](int slot, f32x16& C) -> int {
        return prodP(smem + slot * 1088, C);
    };

    // ---- two interleaved 32-step chunk products (chains: chunk w, chunk w+8) ----
    f32x16 Ca, Cb;
    #pragma unroll
    for (int j = 0; j < 16; ++j) {
        float d = (crow(j, h) == m) ? 1.f : 0.f;        // I (pad diag harmless)
        Ca[j] = d; Cb[j] = d;
    }
    int aE = 0, bE = 0;

    const int cB  = w + 8;
    const int loA = (w == 0) ? 1 : w * 32;
    const int hiA = min(w * 32 + 31, len - 1);
    const int loB = cB * 32;
    const int hiB = min(cB * 32 + 31, len - 1);
    int nA = hiA - loA + 1; if (nA < 0) nA = 0;
    int nB = hiB - loB + 1; if (nB < 0) nB = 0;
    const int n = max(nA, nB);
    const float* efA = smem + w * 1152;
    const float* efB = smem + cB * 1152;

    int lA = hiA, lB = hiB;
    for (int i = 0; i < n; ++i) {
        if (i < nA) { step(Ca, efA, lA - w * 32);  --lA; }
        if (i < nB) { step(Cb, efB, lB - cB * 32); --lB; }
        if ((i & 7) == 7) {                  // strip every 8 (range-safe)
            aE += strip(Ca);
            bE += strip(Cb);
        }
    }
    __syncthreads();   // ef region dead; reuse smem as tree slots

    // ---- tree level 1: P_p = G_{2p} * G_{2p+1} ----
    if ((w & 1) == 0) {
        xwr(w / 2,     Ca, aE);
        xwr(w / 2 + 4, Cb, bE);
    }
    __syncthreads();
    if (w & 1) {
        int pA = (w - 1) / 2;
        aE += EsX[pA]     + prod(pA,     Ca);
        bE += EsX[pA + 4] + prod(pA + 4, Cb);
    }
    __syncthreads();
    // ---- level 2 ----
    if (w == 1 || w == 5) {
        xwr((w - 1) / 4,     Ca, aE);
        xwr((w - 1) / 4 + 2, Cb, bE);
    }
    __syncthreads();
    if (w == 3 || w == 7) {
        int q = (w - 3) / 4;
        aE += EsX[q]     + prod(q,     Ca);
        bE += EsX[q + 2] + prod(q + 2, Cb);
    }
    __syncthreads();
    // ---- level 3 ----
    if (w == 3) {
        xwr(0, Ca, aE);
        xwr(1, Cb, bE);
    }
    __syncthreads();
    if (w == 7) {
        aE += EsX[0] + prod(0, Ca);
        bE += EsX[1] + prod(1, Cb);
    }
    __syncthreads();
    // ---- level 4 (same wave: no barrier between write & read) ----
    if (w == 7) {
        xwr(0, Ca, aE);
        int ex = prodP(smem, Cb);                       // G_total = R_0 * R_1
        int fE = aE + bE + ex;
        float* Gt = smem;                                // Gt[n*34 + r] = G[r][n]
        #pragma unroll
        for (int j = 0; j < 16; ++j) Gt[m * 34 + crow(j, h)] = Cb[j];
        if (lane == 0) EsX[0] = fE;
    }
    __syncthreads();

    // ---- final: part^T = v0^T G_total ; LSE with T[:,STOP] (max-subtracted;
    //      the STOP column is -10000 everywhere!) ----
    if (w == 0) {
        const int n2 = lane & 31;
        float p = (n2 < TAGS) ? (feats[(size_t)b * L * TAGS + n2] + Tm[TSTART * TAGS + n2]) * LOG2E
                              : -1e30f;
        float mx = p;
        #pragma unroll
        for (int off = 32; off; off >>= 1) mx = fmaxf(mx, __shfl_xor(mx, off));
        float v = (n2 < TAGS) ? fexp2(p - mx) : 0.f;
        if (lane < 32) sv[lane] = v;                  // same-wave DS ordering
        const float* Gt = smem;
        float vn = 0.f;
        #pragma unroll
        for (int r = 0; r < 32; r += 2) {
            float2 g2 = *reinterpret_cast<const float2*>(&Gt[n2 * 34 + r]);
            vn = fmaf(sv[r], g2.x, vn);
            vn = fmaf(sv[r + 1], g2.y, vn);
        }
        float cstop = Tm[n2 * TAGS + TSTOP];
        float mc = (n2 < TAGS) ? cstop : -INFINITY;
        #pragma unroll
        for (int off = 32; off; off >>= 1) mc = fmaxf(mc, __shfl_xor(mc, off));
        float ts = (lane < 32 && n2 < TAGS) ? vn * fexp2((cstop - mc) * LOG2E) : 0.f;
        #pragma unroll
        for (int off = 32; off; off >>= 1) ts += __shfl_xor(ts, off);
        if (lane == 0)
            fwd_sh = ((double)mx + (double)EsX[0] + (double)flog2(ts)) * LN2d + (double)mc;
    }

    // ---- gold path score (all 512 threads) ----
    float g = 0.f;
    for (int l = tid; l < len; l += 512) {
        int tt = tags[(size_t)b * L + l];
        int pv = (l == 0) ? TSTART : tags[(size_t)b * L + l - 1];
        g += feats[((size_t)b * L + l) * TAGS + tt] + Tm[pv * TAGS + tt];
    }
    #pragma unroll
    for (int off = 32; off; off >>= 1) g += __shfl_xor(g, off);
    if (lane == 0) gred[w] = g;
    __syncthreads();

    // ---- single-dispatch finish: deterministic fixed-point accumulation
    //      (integer atomics are associative -> bitwise deterministic);
    //      last-arriving block converts and writes d_out (r8-validated) ----
    if (tid == 0) {
        float gs = gred[0] + gred[1] + gred[2] + gred[3]
                 + gred[4] + gred[5] + gred[6] + gred[7];
        double gold = (double)gs + (double)Tm[tags[(size_t)b * L + len - 1] * TAGS + TSTOP];
        double pd   = fwd_sh - gold;
        long long q = (long long)(pd * 1048576.0 + (pd >= 0.0 ? 0.5 : -0.5));  // 2^20 scale
        atomicAdd(acc, (unsigned long long)q);
        __threadfence();
        unsigned int c = atomicAdd(cnt, 1u);
        if (c == gridDim.x - 1) {
            long long tot = (long long)atomicAdd(acc, 0ULL);   // RMW read: coherent
            out[0] = (float)((double)tot * (1.0 / 1048576.0));
        }
    }
}

// ==================== FALLBACK (round-2 serial kernel) ====================
__global__ __launch_bounds__(64)
void crf_fwd_kernel(const float* __restrict__ feats,
                    const float* __restrict__ Tm,
                    const int*   __restrict__ tags,
                    const int*   __restrict__ lengths,
                    double*      __restrict__ partial,
                    int B, int L)
{
    __shared__ float le[512 * TAGS];
    const int b    = blockIdx.x;
    const int lane = threadIdx.x;
    const int j    = (lane < TAGS) ? lane : 0;
    const float* fb  = feats + (size_t)b * L * TAGS;
    const int*   tg  = tags  + (size_t)b * L;
    const int    len = lengths[b];

    const int nv4 = (L * TAGS) >> 2;
    for (int it = lane; it < nv4; it += 64) {
        float4 v = reinterpret_cast<const float4*>(fb)[it];
        float4 e;
        e.x = fexp2(v.x * LOG2E); e.y = fexp2(v.y * LOG2E);
        e.z = fexp2(v.z * LOG2E); e.w = fexp2(v.w * LOG2E);
        reinterpret_cast<float4*>(le)[it] = e;
    }
    __syncthreads();

    float ET[TAGS];
    #pragma unroll
    for (int i = 0; i < TAGS; ++i) ET[i] = fexp2(Tm[i * TAGS + j] * LOG2E);

    float w0   = flog2(le[j]) + Tm[TSTART * TAGS + j] * LOG2E;
    float base = bcast(w0, 0);
    float P    = fexp2(w0 - base);
    float M2   = base;
    float Pa[TAGS];
    #pragma unroll
    for (int i = 0; i < TAGS; ++i) Pa[i] = bcast(P, i);
    const float* leb = le + j;

    auto STEP = [&](int l, float efv, float rsv, bool scaled) {
        float s0 = 0.f, s1 = 0.f, s2 = 0.f, s3 = 0.f;
        #pragma unroll
        for (int i = 0; i < TAGS; i += 4) {
            s0 = fmaf(ET[i + 0], Pa[i + 0], s0);
            s1 = fmaf(ET[i + 1], Pa[i + 1], s1);
            s2 = fmaf(ET[i + 2], Pa[i + 2], s2);
            s3 = fmaf(ET[i + 3], Pa[i + 3], s3);
        }
        float s   = (s0 + s1) + (s2 + s3);
        float cur = s * efv;
        float pn  = (l < len) ? cur : P;
        P = scaled ? pn * rsv : pn;
        #pragma unroll
        for (int i = 0; i < TAGS; ++i) Pa[i] = bcast(P, i);
    };

    float efb[4];
    #pragma unroll
    for (int k = 0; k < 4; ++k) { int ln = 1 + k; ln = (ln < L) ? ln : (L - 1); efb[k] = leb[ln * TAGS]; }

    float rs = 1.0f, lg0 = 0.0f;
    int l0 = 1;
    for (; l0 + 3 < L; l0 += 4) {
        if (l0 >= len) break;
        float efn[4];
        #pragma unroll
        for (int k = 0; k < 4; ++k) { int ln = l0 + 4 + k; ln = (ln < L) ? ln : (L - 1); efn[k] = leb[ln * TAGS]; }
        M2 += lg0;
        STEP(l0 + 0, efb[0], rs, true);
        STEP(l0 + 1, efb[1], 1.f, false);
        STEP(l0 + 2, efb[2], 1.f, false);
        STEP(l0 + 3, efb[3], 1.f, false);
        float p0 = Pa[0];
        rs = frcp(p0); lg0 = flog2(p0);
        #pragma unroll
        for (int k = 0; k < 4; ++k) efb[k] = efn[k];
    }
    if (l0 < len) {
        int rem = L - l0;
        M2 += lg0;
        if (rem > 0) STEP(l0 + 0, efb[0], rs, true);
        if (rem > 1) STEP(l0 + 1, efb[1], 1.f, false);
        if (rem > 2) STEP(l0 + 2, efb[2], 1.f, false);
        if (rem > 3) STEP(l0 + 3, efb[3], 1.f, false);
    }

    float cstop = Tm[j * TAGS + TSTOP];
    float mc = (lane < TAGS) ? cstop : -INFINITY;
    #pragma unroll
    for (int off = 32; off; off >>= 1) mc = fmaxf(mc, __shfl_xor(mc, off));
    float t = (lane < TAGS) ? P * fexp2((cstop - mc) * LOG2E) : 0.f;
    #pragma unroll
    for (int off = 32; off; off >>= 1) t += __shfl_xor(t, off);
    double fwd = ((double)M2 + (double)flog2(t)) * LN2d + (double)mc;

    float g = 0.f;
    for (int l = lane; l < len; l += 64) {
        int tt = tg[l];
        int pv = (l == 0) ? TSTART : tg[l - 1];
        g += flog2(le[l * TAGS + tt]) * LN2f + Tm[pv * TAGS + tt];
    }
    #pragma unroll
    for (int off = 32; off; off >>= 1) g += __shfl_xor(g, off);

    if (lane == 0) {
        double gold = (double)g + (double)Tm[tg[len - 1] * TAGS + TSTOP];
        partial[b] = fwd - gold;
    }
}

__global__ __launch_bounds__(256)
void crf_reduce_kernel(const double* __restrict__ partial, float* __restrict__ out, int B)
{
    __shared__ double sh[256];
    const int t = threadIdx.x;
    double acc = 0.0;
    for (int i = t; i < B; i += 256) acc += partial[i];
    sh[t] = acc;
    __syncthreads();
    for (int s = 128; s; s >>= 1) {
        if (t < s) sh[t] += sh[t + s];
        __syncthreads();
    }
    if (t == 0) out[0] = (float)sh[0];
}

extern "C" void kernel_launch(void* const* d_in, const int* in_sizes, int n_in,
                              void* d_out, int out_size, void* d_ws, size_t ws_size,
                              hipStream_t stream)
{
    const float* feats   = (const float*)d_in[0];
    const float* Tm      = (const float*)d_in[1];
    const int*   tags    = (const int*)d_in[2];
    const int*   lengths = (const int*)d_in[3];

    const int B = in_sizes[3];
    const int L = in_sizes[2] / B;

    if (L == 512 && ws_size >= 64) {
        unsigned long long* acc = (unsigned long long*)d_ws;
        unsigned int*       cnt = (unsigned int*)((char*)d_ws + 8);
        hipMemsetAsync(d_ws, 0, 64, stream);    // zero acc/cnt each call (capture-safe)
        crf_fused_kernel<<<B, 512, 0, stream>>>(feats, Tm, tags, lengths,
                                                acc, cnt, (float*)d_out, L);
    } else {
        double* partial = (double*)((char*)d_ws + 64);
        crf_fwd_kernel<<<B, 64, 0, stream>>>(feats, Tm, tags, lengths, partial, B, L);
        crf_reduce_kernel<<<1, 256, 0, stream>>>(partial, (float*)d_out, B);
    }
}

// Round 15
// 27.460 us; speedup vs baseline: 1.1517x; 1.1517x over previous
//
#include <hip/hip_runtime.h>
#include <hip/hip_bf16.h>
#include <math.h>

#define TAGS   20
#define TSTART (TAGS - 2)
#define TSTOP  (TAGS - 1)

constexpr float  LOG2E = 1.4426950408889634f;
constexpr float  LN2f  = 0.6931471805599453f;
constexpr double LN2d  = 0.69314718055994530942;

typedef __attribute__((ext_vector_type(8)))  short short8;
typedef __attribute__((ext_vector_type(16))) float f32x16;
union U4 { unsigned int u[4]; short8 v; };

// f32x2 -> packed bf16x2, round-half-up (+0x8000 then high halves via one
// v_perm_b32) — validated rounds 7/8/10/11/13, absmax 0.0. 3 VALU ops.
__device__ __forceinline__ unsigned int pk2(float lo, float hi) {
    unsigned int a = __float_as_uint(hi) + 0x8000u;
    unsigned int b = __float_as_uint(lo) + 0x8000u;
#if __has_builtin(__builtin_amdgcn_perm)
    return __builtin_amdgcn_perm(a, b, 0x07060302u);   // {a[31:16], b[31:16]}
#else
    return (a & 0xFFFF0000u) | (b >> 16);
#endif
}
#if __has_builtin(__builtin_amdgcn_exp2f)
__device__ __forceinline__ float fexp2(float x) { return __builtin_amdgcn_exp2f(x); }
#else
__device__ __forceinline__ float fexp2(float x) { return exp2f(x); }
#endif
#if __has_builtin(__builtin_amdgcn_logf)
__device__ __forceinline__ float flog2(float x) { return __builtin_amdgcn_logf(x); }
#else
__device__ __forceinline__ float flog2(float x) { return log2f(x); }
#endif
__device__ __forceinline__ float frcp(float x) { return __builtin_amdgcn_rcpf(x); }
__device__ __forceinline__ float bcast(float v, int srclane) {
    return __int_as_float(__builtin_amdgcn_readlane(__float_as_int(v), srclane));
}

// 32x32x16 split-half A/B k-slot base (validated rounds 11/13, absmax 0.0).
__device__ __forceinline__ int kbase(int p, int h) {
    return (p < 2) ? (4 * h + 2 * p) : (8 + 4 * h + 2 * (p - 2));
}
// 32x32 C/D row for reg j, lane-half h (guide-verified m74/m101)
__device__ __forceinline__ int crow(int j, int h) {
    return (j & 3) + 8 * (j >> 2) + 4 * h;
}

#define EFSTRIDE 36   // ef row stride (floats): 16B-aligned, bank-spread stores

// ========================== FUSED KERNEL ==================================
// Round-13 body (best measured: 27.9us, absmax 0.0) with the gold-path
// score HOISTED before the chunk loop: its scattered global gathers have no
// dependencies, so their HBM/L2 latency hides under the 32-step MFMA chain
// instead of running serially after the tree. The tid==0 epilogue is folded
// into the w==0 LSE block (gred[] is barrier-covered; lane 0 holds fwd).
__global__ __launch_bounds__(512)
void crf_fused_kernel(const float* __restrict__ feats,
                      const float* __restrict__ Tm,
                      const int*   __restrict__ tags,
                      const int*   __restrict__ lengths,
                      double*      __restrict__ partial,
                      int L)
{
    __shared__ float  smem[16 * 1152];   // 72 KB: ef staging; later tree slots (stride 1088)
    __shared__ float  sv[32];
    __shared__ int    EsX[8];
    __shared__ float  gred[8];

    const int b    = blockIdx.x;
    const int tid  = threadIdx.x;
    const int w    = tid >> 6;
    const int lane = tid & 63;
    const int m    = lane & 31;          // output row (A) / column (C,B)
    const int h    = lane >> 5;          // lane half
    const int len  = lengths[b];

    // ---- stage ef = 2^(feat*log2e): lane (h,r) owns chunk w+8h, row r ----
    // 5 aligned float4 loads, 20 exp2, 8 float4 LDS stores. No divisions.
    // Wave w reads only its own staged chunks -> same-wave DS ordering,
    // no barrier needed (r8/r10/r13-validated).
    {
        const int r = lane & 31;
        const int c = w + 8 * (lane >> 5);
        float* efc = smem + c * 1152;
        const float4* p = reinterpret_cast<const float4*>(
            feats + ((size_t)b * L + (size_t)c * 32 + r) * TAGS);
        float4 o[5];
        #pragma unroll
        for (int j = 0; j < 5; ++j) {
            float4 v = p[j];
            o[j].x = fexp2(v.x * LOG2E); o[j].y = fexp2(v.y * LOG2E);
            o[j].z = fexp2(v.z * LOG2E); o[j].w = fexp2(v.w * LOG2E);
        }
        float4* q = reinterpret_cast<float4*>(efc + r * EFSTRIDE);
        #pragma unroll
        for (int j = 0; j < 5; ++j) q[j] = o[j];
        float4 z4 = make_float4(0.f, 0.f, 0.f, 0.f);
        q[5] = z4; q[6] = z4; q[7] = z4; q[8] = z4;
    }

    // ---- gold path score (hoisted: no deps; latency hides under chunk loop) ----
    {
        float g = 0.f;
        for (int l = tid; l < len; l += 512) {
            int tt = tags[(size_t)b * L + l];
            int pv = (l == 0) ? TSTART : tags[(size_t)b * L + l - 1];
            g += feats[((size_t)b * L + l) * TAGS + tt] + Tm[pv * TAGS + tt];
        }
        #pragma unroll
        for (int off = 32; off; off >>= 1) g += __shfl_xor(g, off);
        if (lane == 0) gred[w] = g;    // visible to wave 0 after the tree's barriers
    }

    // ---- constant A fragments: A1 = 2^T[:,k<16], A2 = 2^T[:,k>=16] ----
    U4 A1g, A2g;
    #pragma unroll
    for (int p = 0; p < 4; ++p) {
        int r = kbase(p, h);
        float a0 = (m < TAGS && r     < TAGS) ? fexp2(Tm[m * TAGS + r]      * LOG2E) : 0.f;
        float a1 = (m < TAGS && r + 1 < TAGS) ? fexp2(Tm[m * TAGS + r + 1]  * LOG2E) : 0.f;
        float b0 = (m < TAGS && r + 16 < TAGS) ? fexp2(Tm[m * TAGS + r + 16] * LOG2E) : 0.f;
        float b1 = (m < TAGS && r + 17 < TAGS) ? fexp2(Tm[m * TAGS + r + 17] * LOG2E) : 0.f;
        A1g.u[p] = pk2(a0, a1);
        A2g.u[p] = pk2(b0, b1);
    }

    // step: C <- ET * (D_l * C) via 2 MFMAs (C-in chained)
    auto step = [&](f32x16& C, const float* efc, int t) {
        const float* row = efc + t * EFSTRIDE;
        float4 ea = *reinterpret_cast<const float4*>(row + 4 * h);
        float4 eb = *reinterpret_cast<const float4*>(row + 8 + 4 * h);
        float4 ec = *reinterpret_cast<const float4*>(row + 16 + 4 * h);
        float4 ed = *reinterpret_cast<const float4*>(row + 24 + 4 * h);
        U4 B1, B2;
        B1.u[0] = pk2(C[0]  * ea.x, C[1]  * ea.y);
        B1.u[1] = pk2(C[2]  * ea.z, C[3]  * ea.w);
        B1.u[2] = pk2(C[4]  * eb.x, C[5]  * eb.y);
        B1.u[3] = pk2(C[6]  * eb.z, C[7]  * eb.w);
        B2.u[0] = pk2(C[8]  * ec.x, C[9]  * ec.y);
        B2.u[1] = pk2(C[10] * ec.z, C[11] * ec.w);
        B2.u[2] = pk2(C[12] * ed.x, C[13] * ed.y);
        B2.u[3] = pk2(C[14] * ed.z, C[15] * ed.w);
        f32x16 z = {0.f,0.f,0.f,0.f,0.f,0.f,0.f,0.f,0.f,0.f,0.f,0.f,0.f,0.f,0.f,0.f};
        f32x16 t1 = __builtin_amdgcn_mfma_f32_32x32x16_bf16(A1g.v, B1.v, z,  0, 0, 0);
        C         = __builtin_amdgcn_mfma_f32_32x32x16_bf16(A2g.v, B2.v, t1, 0, 0, 0);
    };
    auto strip = [&](f32x16& C) -> int {
        float pr = ((C[0]+C[1])+(C[2]+C[3])) + ((C[4]+C[5])+(C[6]+C[7]))
                 + ((C[8]+C[9])+(C[10]+C[11])) + ((C[12]+C[13])+(C[14]+C[15]));
        int pb = __builtin_amdgcn_readfirstlane(__float_as_int(pr)); // col0 half-sum, >0
        int ex = ((pb >> 23) & 0xFF) - 127;
        float s = __uint_as_float((unsigned)(127 - ex) << 23);       // 2^-ex
        #pragma unroll
        for (int j = 0; j < 16; ++j) C[j] *= s;
        return ex;
    };
    auto xwrP = [&](float* Xs, const f32x16& C) {       // row-major, stride 34
        #pragma unroll
        for (int j = 0; j < 16; ++j) Xs[crow(j, h) * 34 + m] = C[j];
    };
    auto prodP = [&](const float* Xs, f32x16& C) -> int {  // C <- X * C
        U4 Ax1, Ax2;
        #pragma unroll
        for (int p = 0; p < 4; ++p) {
            int r = kbase(p, h);
            float2 x1 = *reinterpret_cast<const float2*>(&Xs[m * 34 + r]);
            float2 x2 = *reinterpret_cast<const float2*>(&Xs[m * 34 + r + 16]);
            Ax1.u[p] = pk2(x1.x, x1.y);
            Ax2.u[p] = pk2(x2.x, x2.y);
        }
        U4 B1, B2;
        B1.u[0] = pk2(C[0],  C[1]);
        B1.u[1] = pk2(C[2],  C[3]);
        B1.u[2] = pk2(C[4],  C[5]);
        B1.u[3] = pk2(C[6],  C[7]);
        B2.u[0] = pk2(C[8],  C[9]);
        B2.u[1] = pk2(C[10], C[11]);
        B2.u[2] = pk2(C[12], C[13]);
        B2.u[3] = pk2(C[14], C[15]);
        f32x16 z = {0.f,0.f,0.f,0.f,0.f,0.f,0.f,0.f,0.f,0.f,0.f,0.f,0.f,0.f,0.f,0.f};
        f32x16 t1 = __builtin_amdgcn_mfma_f32_32x32x16_bf16(Ax1.v, B1.v, z,  0, 0, 0);
        C         = __builtin_amdgcn_mfma_f32_32x32x16_bf16(Ax2.v, B2.v, t1, 0, 0, 0);
        return strip(C);
    };
    auto xwr = [&](int slot, const f32x16& C, int E) {
        xwrP(smem + slot * 1088, C);
        if (lane == 0) EsX[slot] = E;
    };
    auto prod = [&](int slot, f32x16& C) -> int {
        return prodP(smem + slot * 1088, C);
    };

    // ---- two interleaved 32-step chunk products (chains: chunk w, chunk w+8) ----
    f32x16 Ca, Cb;
    #pragma unroll
    for (int j = 0; j < 16; ++j) {
        float d = (crow(j, h) == m) ? 1.f : 0.f;        // I (pad diag harmless)
        Ca[j] = d; Cb[j] = d;
    }
    int aE = 0, bE = 0;

    const int cB  = w + 8;
    const int loA = (w == 0) ? 1 : w * 32;
    const int hiA = min(w * 32 + 31, len - 1);
    const int loB = cB * 32;
    const int hiB = min(cB * 32 + 31, len - 1);
    int nA = hiA - loA + 1; if (nA < 0) nA = 0;
    int nB = hiB - loB + 1; if (nB < 0) nB = 0;
    const int n = max(nA, nB);
    const float* efA = smem + w * 1152;
    const float* efB = smem + cB * 1152;

    int lA = hiA, lB = hiB;
    for (int i = 0; i < n; ++i) {
        if (i < nA) { step(Ca, efA, lA - w * 32);  --lA; }
        if (i < nB) { step(Cb, efB, lB - cB * 32); --lB; }
        if ((i & 7) == 7) {                  // strip every 8 (range-safe)
            aE += strip(Ca);
            bE += strip(Cb);
        }
    }
    __syncthreads();   // ef region dead; reuse smem as tree slots

    // ---- tree level 1: P_p = G_{2p} * G_{2p+1} ----
    if ((w & 1) == 0) {
        xwr(w / 2,     Ca, aE);
        xwr(w / 2 + 4, Cb, bE);
    }
    __syncthreads();
    if (w & 1) {
        int pA = (w - 1) / 2;
        aE += EsX[pA]     + prod(pA,     Ca);
        bE += EsX[pA + 4] + prod(pA + 4, Cb);
    }
    __syncthreads();
    // ---- level 2 ----
    if (w == 1 || w == 5) {
        xwr((w - 1) / 4,     Ca, aE);
        xwr((w - 1) / 4 + 2, Cb, bE);
    }
    __syncthreads();
    if (w == 3 || w == 7) {
        int q = (w - 3) / 4;
        aE += EsX[q]     + prod(q,     Ca);
        bE += EsX[q + 2] + prod(q + 2, Cb);
    }
    __syncthreads();
    // ---- level 3 ----
    if (w == 3) {
        xwr(0, Ca, aE);
        xwr(1, Cb, bE);
    }
    __syncthreads();
    if (w == 7) {
        aE += EsX[0] + prod(0, Ca);
        bE += EsX[1] + prod(1, Cb);
    }
    __syncthreads();
    // ---- level 4 (same wave: no barrier between write & read) ----
    if (w == 7) {
        xwr(0, Ca, aE);
        int ex = prodP(smem, Cb);                       // G_total = R_0 * R_1
        int fE = aE + bE + ex;
        float* Gt = smem;                                // Gt[n*34 + r] = G[r][n]
        #pragma unroll
        for (int j = 0; j < 16; ++j) Gt[m * 34 + crow(j, h)] = Cb[j];
        if (lane == 0) EsX[0] = fE;
    }
    __syncthreads();

    // ---- final: part^T = v0^T G_total ; LSE with T[:,STOP] (max-subtracted;
    //      the STOP column is -10000 everywhere!); epilogue folded in ----
    if (w == 0) {
        const int n2 = lane & 31;
        float p = (n2 < TAGS) ? (feats[(size_t)b * L * TAGS + n2] + Tm[TSTART * TAGS + n2]) * LOG2E
                              : -1e30f;
        float mx = p;
        #pragma unroll
        for (int off = 32; off; off >>= 1) mx = fmaxf(mx, __shfl_xor(mx, off));
        float v = (n2 < TAGS) ? fexp2(p - mx) : 0.f;
        if (lane < 32) sv[lane] = v;                  // same-wave DS ordering
        const float* Gt = smem;
        float vn = 0.f;
        #pragma unroll
        for (int r = 0; r < 32; r += 2) {
            float2 g2 = *reinterpret_cast<const float2*>(&Gt[n2 * 34 + r]);
            vn = fmaf(sv[r], g2.x, vn);
            vn = fmaf(sv[r + 1], g2.y, vn);
        }
        float cstop = Tm[n2 * TAGS + TSTOP];
        float mc = (n2 < TAGS) ? cstop : -INFINITY;
        #pragma unroll
        for (int off = 32; off; off >>= 1) mc = fmaxf(mc, __shfl_xor(mc, off));
        float ts = (lane < 32 && n2 < TAGS) ? vn * fexp2((cstop - mc) * LOG2E) : 0.f;
        #pragma unroll
        for (int off = 32; off; off >>= 1) ts += __shfl_xor(ts, off);
        if (lane == 0) {
            double fwd = ((double)mx + (double)EsX[0] + (double)flog2(ts)) * LN2d + (double)mc;
            float gs = gred[0] + gred[1] + gred[2] + gred[3]
                     + gred[4] + gred[5] + gred[6] + gred[7];
            double gold = (double)gs + (double)Tm[tags[(size_t)b * L + len - 1] * TAGS + TSTOP];
            partial[b] = fwd - gold;
        }
    }
}

// ==================== FALLBACK (round-2 serial kernel) ====================
__global__ __launch_bounds__(64)
void crf_fwd_kernel(const float* __restrict__ feats,
                    const float* __restrict__ Tm,
                    const int*   __restrict__ tags,
                    const int*   __restrict__ lengths,
                    double*      __restrict__ partial,
                    int B, int L)
{
    __shared__ float le[512 * TAGS];
    const int b    = blockIdx.x;
    const int lane = threadIdx.x;
    const int j    = (lane < TAGS) ? lane : 0;
    const float* fb  = feats + (size_t)b * L * TAGS;
    const int*   tg  = tags  + (size_t)b * L;
    const int    len = lengths[b];

    const int nv4 = (L * TAGS) >> 2;
    for (int it = lane; it < nv4; it += 64) {
        float4 v = reinterpret_cast<const float4*>(fb)[it];
        float4 e;
        e.x = fexp2(v.x * LOG2E); e.y = fexp2(v.y * LOG2E);
        e.z = fexp2(v.z * LOG2E); e.w = fexp2(v.w * LOG2E);
        reinterpret_cast<float4*>(le)[it] = e;
    }
    __syncthreads();

    float ET[TAGS];
    #pragma unroll
    for (int i = 0; i < TAGS; ++i) ET[i] = fexp2(Tm[i * TAGS + j] * LOG2E);

    float w0   = flog2(le[j]) + Tm[TSTART * TAGS + j] * LOG2E;
    float base = bcast(w0, 0);
    float P    = fexp2(w0 - base);
    float M2   = base;
    float Pa[TAGS];
    #pragma unroll
    for (int i = 0; i < TAGS; ++i) Pa[i] = bcast(P, i);
    const float* leb = le + j;

    auto STEP = [&](int l, float efv, float rsv, bool scaled) {
        float s0 = 0.f, s1 = 0.f, s2 = 0.f, s3 = 0.f;
        #pragma unroll
        for (int i = 0; i < TAGS; i += 4) {
            s0 = fmaf(ET[i + 0], Pa[i + 0], s0);
            s1 = fmaf(ET[i + 1], Pa[i + 1], s1);
            s2 = fmaf(ET[i + 2], Pa[i + 2], s2);
            s3 = fmaf(ET[i + 3], Pa[i + 3], s3);
        }
        float s   = (s0 + s1) + (s2 + s3);
        float cur = s * efv;
        float pn  = (l < len) ? cur : P;
        P = scaled ? pn * rsv : pn;
        #pragma unroll
        for (int i = 0; i < TAGS; ++i) Pa[i] = bcast(P, i);
    };

    float efb[4];
    #pragma unroll
    for (int k = 0; k < 4; ++k) { int ln = 1 + k; ln = (ln < L) ? ln : (L - 1); efb[k] = leb[ln * TAGS]; }

    float rs = 1.0f, lg0 = 0.0f;
    int l0 = 1;
    for (; l0 + 3 < L; l0 += 4) {
        if (l0 >= len) break;
        float efn[4];
        #pragma unroll
        for (int k = 0; k < 4; ++k) { int ln = l0 + 4 + k; ln = (ln < L) ? ln : (L - 1); efn[k] = leb[ln * TAGS]; }
        M2 += lg0;
        STEP(l0 + 0, efb[0], rs, true);
        STEP(l0 + 1, efb[1], 1.f, false);
        STEP(l0 + 2, efb[2], 1.f, false);
        STEP(l0 + 3, efb[3], 1.f, false);
        float p0 = Pa[0];
        rs = frcp(p0); lg0 = flog2(p0);
        #pragma unroll
        for (int k = 0; k < 4; ++k) efb[k] = efn[k];
    }
    if (l0 < len) {
        int rem = L - l0;
        M2 += lg0;
        if (rem > 0) STEP(l0 + 0, efb[0], rs, true);
        if (rem > 1) STEP(l0 + 1, efb[1], 1.f, false);
        if (rem > 2) STEP(l0 + 2, efb[2], 1.f, false);
        if (rem > 3) STEP(l0 + 3, efb[3], 1.f, false);
    }

    float cstop = Tm[j * TAGS + TSTOP];
    float mc = (lane < TAGS) ? cstop : -INFINITY;
    #pragma unroll
    for (int off = 32; off; off >>= 1) mc = fmaxf(mc, __shfl_xor(mc, off));
    float t = (lane < TAGS) ? P * fexp2((cstop - mc) * LOG2E) : 0.f;
    #pragma unroll
    for (int off = 32; off; off >>= 1) t += __shfl_xor(t, off);
    double fwd = ((double)M2 + (double)flog2(t)) * LN2d + (double)mc;

    float g = 0.f;
    for (int l = lane; l < len; l += 64) {
        int tt = tg[l];
        int pv = (l == 0) ? TSTART : tg[l - 1];
        g += flog2(le[l * TAGS + tt]) * LN2f + Tm[pv * TAGS + tt];
    }
    #pragma unroll
    for (int off = 32; off; off >>= 1) g += __shfl_xor(g, off);

    if (lane == 0) {
        double gold = (double)g + (double)Tm[tg[len - 1] * TAGS + TSTOP];
        partial[b] = fwd - gold;
    }
}

__global__ __launch_bounds__(256)
void crf_reduce_kernel(const double* __restrict__ partial, float* __restrict__ out, int B)
{
    __shared__ double sh[256];
    const int t = threadIdx.x;
    double acc = 0.0;
    for (int i = t; i < B; i += 256) acc += partial[i];
    sh[t] = acc;
    __syncthreads();
    for (int s = 128; s; s >>= 1) {
        if (t < s) sh[t] += sh[t + s];
        __syncthreads();
    }
    if (t == 0) out[0] = (float)sh[0];
}

extern "C" void kernel_launch(void* const* d_in, const int* in_sizes, int n_in,
                              void* d_out, int out_size, void* d_ws, size_t ws_size,
                              hipStream_t stream)
{
    const float* feats   = (const float*)d_in[0];
    const float* Tm      = (const float*)d_in[1];
    const int*   tags    = (const int*)d_in[2];
    const int*   lengths = (const int*)d_in[3];

    const int B = in_sizes[3];
    const int L = in_sizes[2] / B;

    double* partial = (double*)d_ws;

    if (L == 512 && ws_size >= (size_t)B * sizeof(double)) {
        crf_fused_kernel<<<B, 512, 0, stream>>>(feats, Tm, tags, lengths, partial, L);
        crf_reduce_kernel<<<1, 256, 0, stream>>>(partial, (float*)d_out, B);
    } else {
        crf_fwd_kernel<<<B, 64, 0, stream>>>(feats, Tm, tags, lengths, partial, B, L);
        crf_reduce_kernel<<<1, 256, 0, stream>>>(partial, (float*)d_out, B);
    }
}